// Round 9
// baseline (227.478 us; speedup 1.0000x reference)
//
#include <hip/hip_runtime.h>

// ============================================================================
// ContDecoder on MI355X — bf16 MFMA, round 11: cross-barrier weight prefetch.
// MPTS=32, 1024 threads (16 waves), 55.8 KB dynamic LDS, 2 blocks/CU.
//
// r7/r9/r10 falsified all throughput theories: runtime invariant under
// halved LDS traffic, halved MFMA count, 8x fewer conflicts. Model: phase-
// structure-bound — post-barrier thundering-herd (16 waves issue weight
// loads simultaneously, ~300+cyc L2 ramp) x 8 phases, correlated waits.
// Round-11 levers:
//   (1) T14 cross-barrier prefetch: each wave issues its first-2-K-step
//       B-frag (weight) loads for layer l+1 BEFORE the layer-l barrier.
//       Weights depend on nothing the barrier protects; the barrier fence
//       PINS the loads (compiler cannot sink them past it — defeats the
//       sinking that nulled r5/r6/r8 pipelining). Phase starts begin with
//       data in flight.
//   (2) Prologue barrier merge: bilinear params recomputed inline per
//       sample (all written cols disjoint) -> 1 pre-L0 barrier, not 2.
// Base = r8 (best, 144.7us): 16x16x32, swapped operands mfma(W,X)->D[n,pt],
// ds_write_b64 epilogue + float4 bias. SGB stream dropped (null, r8).
//
// LDS row layout per point (bf16): [xin 0..64 | hA 64..608 | hB 608..864],
// stride 872 elems. Stale bytes in reused regions are masked by zero-packed
// weight rows; pad neurons get bias 0 so they write exact zeros.
// ============================================================================

#define NTH     1024
#define NWAVES  16
#define MPTS    32              // points per block (2 m-tiles of 16)
#define MTILES  (MPTS / 16)
#define SROW    872             // LDS row stride in bf16 elems
#define XIN_OFF 0
#define HA_OFF  64
#define HB_OFF  608
#define NPOINTS (8 * 16384)
#define GRIDX   (NPOINTS / MPTS)   // 4096 blocks
#define LDSBYTES (MPTS * SROW * 2) // 55808 -> 2 blocks/CU

typedef short          short8  __attribute__((ext_vector_type(8)));
typedef short          short4v __attribute__((ext_vector_type(4)));
typedef float          f32x4   __attribute__((ext_vector_type(4)));
typedef unsigned short u16;

struct TrueT  { static constexpr bool value = true;  };
struct FalseT { static constexpr bool value = false; };

__device__ __forceinline__ u16 f2bf(float f) {
    unsigned int u = __builtin_bit_cast(unsigned int, f);
    u += 0x7fffu + ((u >> 16) & 1u);        // round-to-nearest-even
    return (u16)(u >> 16);
}

// ---------------------------------------------------------------------------
// Packed-weight geometry (16B fragments of 8 bf16). frag (l, nt, s, lane)
// holds B[s*32 + (lane>>4)*8 + j][nt*16 + (lane&15)], j=0..7, zero-padded.
// Identical byte layout as A- or B-operand of mfma_16x16x32 (HW-verified:
// r6/r7/r8 swapped-operand kernels passed). Same pack as r4..r9.
//   l : KHpad KSteps Ntiles  frag_base
//   0 :    0    2     33        0
//   1 :  544   19     16     4224
//   2 :  256   10      8    23680
//   3 :  128    6      4    28800
//   4 :   64    4      2    30336
//   5 :   32    3      1    30848
//   6 :   32    1      1    31040   total 31104 frags = 497664 B in d_ws
// ---------------------------------------------------------------------------
__constant__ int pk_base8[8] = {0, 4224, 23680, 28800, 30336, 30848, 31040, 31104};
__constant__ int pk_ks[7]    = {2, 19, 10, 6, 4, 3, 1};
__constant__ int pk_khp[7]   = {0, 544, 256, 128, 64, 32, 32};
__constant__ int pk_kact[7]  = {0, 516, 256, 128, 64, 32, 16};
__constant__ int pk_nact[7]  = {516, 256, 128, 64, 32, 16, 2};

struct WPtrs { const float* W[7]; };

__global__ void pack_weights(WPtrs wp, u16* __restrict__ out)
{
    const int f = blockIdx.x * blockDim.x + threadIdx.x;
    if (f >= 31104) return;
    int l = 0;
    while (l < 6 && f >= pk_base8[l + 1]) ++l;
    const int r    = f - pk_base8[l];
    const int lane = r & 63;
    const int t    = r >> 6;
    const int ks   = pk_ks[l];
    const int s    = t % ks;
    const int nt   = t / ks;
    const int n    = nt * 16 + (lane & 15);
    const int k0   = s * 32 + (lane >> 4) * 8;
    const int nact = pk_nact[l];
    const int khp  = pk_khp[l];
    const int kact = pk_kact[l];
    const float* W = wp.W[l];

    union { short8 v; u16 e[8]; } frag;
#pragma unroll
    for (int j = 0; j < 8; ++j) {
        const int k = k0 + j;
        float v = 0.0f;
        if (n < nact) {
            if (k < khp) {
                if (k < kact) v = W[k * nact + n];
            } else {
                const int xr = k - khp;
                if (xr < 37) v = W[(kact + xr) * nact + n];
            }
        }
        frag.e[j] = f2bf(v);
    }
    *(short8*)(out + (size_t)f * 8) = frag.v;
}

// ---------------------------------------------------------------------------
// Cross-barrier prefetch: the wave's first next-layer unit is nt=wave.
// Issue B-frags for k-steps 0..1 BEFORE the barrier; the barrier fence pins
// the loads above it, so they are in flight during the drain + next phase.
// ---------------------------------------------------------------------------
struct PF2 { short8 b0, b1; };

template<int KS, int LBASE, int NT>
__device__ __forceinline__ PF2 prefetch(const u16* __restrict__ wpack,
                                        int wave, int lane)
{
    PF2 pf;
    if (wave < NT) {
        const u16* bp = wpack + LBASE + lane * 8 + (size_t)wave * KS * 512;
        pf.b0 = *(const short8*)(bp);
        if constexpr (KS > 1) pf.b1 = *(const short8*)(bp + 512);
    }
    return pf;
}

// ---------------------------------------------------------------------------
// One MLP layer, r8 mapping: wave w handles n-tiles {w, w+16, ...} < NT,
// both m-tiles (MS=2). Per K-step: 2 ds_read_b128 (A) + 1 global load (B)
// + 2 MFMA (swapped: D[n,pt]). First unit's steps 0..1 consume the
// prefetched frags. D: col pt = lane&15, row n = (lane>>4)*4 + r.
// ---------------------------------------------------------------------------
template<int KHP, int HSEG, int OSEG, int NT, int NACT, int LBASE,
         bool XIN, bool RELU, bool GOUT>
__device__ __forceinline__ void mlayer(const u16* __restrict__ wpack,
                                       const float* __restrict__ bias,
                                       u16* __restrict__ s_act,
                                       float* __restrict__ gout, int p0,
                                       int wave, int lane, const PF2 pf)
{
    constexpr int KHS = KHP / 32;
    constexpr int KS  = KHS + (XIN ? 2 : 0);
    constexpr int MS  = MTILES;        // 2 m-tiles, both owned by each wave
    const int lm = lane & 15;
    const int lq = lane >> 4;
    const u16* wl = wpack + LBASE + lane * 8;

    const u16* arow[MS];
#pragma unroll
    for (int m = 0; m < MS; ++m)
        arow[m] = s_act + (m * 16 + lm) * SROW + lq * 8;

    auto unit = [&](int nt, auto usepf) {
        constexpr bool USEPF = decltype(usepf)::value;
        const u16* bp = wl + (size_t)nt * KS * 512;

        f32x4 acc[MS];
#pragma unroll
        for (int m = 0; m < MS; ++m)
            acc[m] = (f32x4){0.f, 0.f, 0.f, 0.f};

#pragma unroll
        for (int s = 0; s < KS; ++s) {
            const int ab = (s < KHS) ? (HSEG + s * 32)
                                     : (XIN_OFF + (s - KHS) * 32);
            short8 a[MS];
#pragma unroll
            for (int m = 0; m < MS; ++m)
                a[m] = *(const short8*)(arow[m] + ab);
            short8 b;
            bool got = false;
            if constexpr (USEPF) {
                if (s == 0) { b = pf.b0; got = true; }
                if constexpr (KS > 1) { if (s == 1) { b = pf.b1; got = true; } }
            }
            if (!got) b = *(const short8*)(bp + (size_t)s * 512);
#pragma unroll
            for (int m = 0; m < MS; ++m)
                acc[m] = __builtin_amdgcn_mfma_f32_16x16x32_bf16(b, a[m], acc[m], 0, 0, 0);
        }

        // ---- epilogue: lane lm = point, 4 consecutive n per lane ----
        const int bn = nt * 16 + lq * 4;
        float bv[4];
        if (bn + 4 <= NACT) {
            const f32x4 b4 = *(const f32x4*)(bias + bn);
            bv[0] = b4[0]; bv[1] = b4[1]; bv[2] = b4[2]; bv[3] = b4[3];
        } else {
#pragma unroll
            for (int r = 0; r < 4; ++r)
                bv[r] = (bn + r < NACT) ? bias[bn + r] : 0.f;
        }
        if (GOUT) {
            if (lq == 0) {             // only n=0,1 valid (NACT=2)
#pragma unroll
                for (int m = 0; m < MS; ++m) {
                    float2 o;
                    o.x = acc[m][0] + bv[0];
                    o.y = acc[m][1] + bv[1];
                    *(float2*)(gout + (size_t)(p0 + m * 16 + lm) * 2) = o;
                }
            }
        } else {
#pragma unroll
            for (int m = 0; m < MS; ++m) {
                short4v o;
#pragma unroll
                for (int r = 0; r < 4; ++r) {
                    float v = acc[m][r] + bv[r];
                    if (RELU) v = fmaxf(v, 0.f);
                    o[r] = (short)f2bf(v);
                }
                *(short4v*)(s_act + (size_t)(m * 16 + lm) * SROW + OSEG + bn) = o;
            }
        }
    };

    if (wave < NT) {
        unit(wave, TrueT{});
        for (int nt = wave + NWAVES; nt < NT; nt += NWAVES)
            unit(nt, FalseT{});
    }
}

struct MainParams {
    const float* lr;     // [B,2,64,64]
    const float* ctx;    // [B,32,64,64]
    const float* eps;    // [B,64,64]
    const float* coord;  // [B,N,2]
    const float* Bb[7];  // biases (fp32)
    const u16*   wpack;  // packed bf16 weights in d_ws
    float*       out;    // [B,N,2]
};

__global__ __launch_bounds__(NTH, 8)   // 8 waves/EU = 32 waves/CU = 2 blocks
void cont_decoder_mfma(MainParams p)
{
    extern __shared__ u16 s_act[];         // MPTS*SROW bf16 = 55808 B

    const int tid  = threadIdx.x;
    const int wave = tid >> 6;
    const int lane = tid & 63;
    const int p0   = blockIdx.x * MPTS;
    const int b    = p0 >> 14;             // 16384 points per batch

    // ---- zero pad regions: xin[37..64) and hA[528..544) (cols 592..608) ----
    for (int i = tid; i < MPTS * 43; i += NTH) {
        const int pt = i / 43, c = i % 43;
        const int col = (c < 27) ? (37 + c) : (592 + (c - 27));
        s_act[pt * SROW + col] = 0;
    }

    // ---- sampling + coord features, single phase (bilinear params inline;
    //      all written cols disjoint -> no intra-prologue barrier) ----
    for (int idx = tid; idx < MPTS * 36; idx += NTH) {
        const int t = idx / 36;
        const int c = idx % 36;
        const int pt = p0 + t;
        const float cx = p.coord[2 * pt];
        const float cy = p.coord[2 * pt + 1];

        if (c == 35) {                      // coord feature cols 32,33
            s_act[t * SROW + 32] = f2bf(cx);
            s_act[t * SROW + 33] = f2bf(cy);
            continue;
        }

        const float gx = (cx + 1.0f) * 32.0f - 0.5f;   // align_corners=False
        const float gy = (cy + 1.0f) * 32.0f - 0.5f;
        const float fx0 = floorf(gx), fy0 = floorf(gy);
        const int   x0 = (int)fx0,  y0 = (int)fy0;
        const float wx = gx - fx0,  wy = gy - fy0;

        const float* base;
        int col;
        if (c < 32)      { base = p.ctx + (size_t)(b * 32 + c) * 4096;       col = c; }
        else if (c < 34) { base = p.lr  + (size_t)(b * 2 + (c - 32)) * 4096; col = 34 + (c - 32); }
        else             { base = p.eps + (size_t)b * 4096;                   col = 36; }

        const int x1 = x0 + 1, y1 = y0 + 1;
        const bool xv0 = (x0 >= 0) & (x0 < 64);
        const bool xv1 = (x1 >= 0) & (x1 < 64);
        const bool yv0 = (y0 >= 0) & (y0 < 64);
        const bool yv1 = (y1 >= 0) & (y1 < 64);
        const int xc0 = min(max(x0, 0), 63), xc1 = min(max(x1, 0), 63);
        const int yc0 = min(max(y0, 0), 63), yc1 = min(max(y1, 0), 63);

        const float w00 = (1.0f - wx) * (1.0f - wy) * ((xv0 && yv0) ? 1.0f : 0.0f);
        const float w10 = wx * (1.0f - wy)          * ((xv1 && yv0) ? 1.0f : 0.0f);
        const float w01 = (1.0f - wx) * wy          * ((xv0 && yv1) ? 1.0f : 0.0f);
        const float w11 = wx * wy                   * ((xv1 && yv1) ? 1.0f : 0.0f);

        const float val = w00 * base[xc0 * 64 + yc0]
                        + w10 * base[xc1 * 64 + yc0]
                        + w01 * base[xc0 * 64 + yc1]
                        + w11 * base[xc1 * 64 + yc1];
        s_act[t * SROW + col] = f2bf(val);
    }

    // ---- MLP:  xin(37p64) ->W0-> hA(516p528) ->W1-> hB(256) ->W2-> hA(128)
    //            ->W3-> hB(64) ->W4-> hA(32) ->W5-> hB(16) ->W6-> out(2)
    // Prefetch for layer l+1 issued BEFORE layer-l barrier (fence-pinned).
    //       KHP  HSEG    OSEG    NT  NACT LBASE   XIN   RELU   GOUT
    PF2 pf = prefetch< 2, 0,      33>(p.wpack, wave, lane);
    __syncthreads();
    mlayer<  0,  HA_OFF, HA_OFF, 33, 516, 0,      true,  true,  false>(p.wpack, p.Bb[0], s_act, nullptr, p0, wave, lane, pf);
    pf = prefetch<19, 33792, 16>(p.wpack, wave, lane);
    __syncthreads();
    mlayer<544,  HA_OFF, HB_OFF, 16, 256, 33792,  true,  true,  false>(p.wpack, p.Bb[1], s_act, nullptr, p0, wave, lane, pf);
    pf = prefetch<10, 189440, 8>(p.wpack, wave, lane);
    __syncthreads();
    mlayer<256,  HB_OFF, HA_OFF,  8, 128, 189440, true,  true,  false>(p.wpack, p.Bb[2], s_act, nullptr, p0, wave, lane, pf);
    pf = prefetch< 6, 230400, 4>(p.wpack, wave, lane);
    __syncthreads();
    mlayer<128,  HA_OFF, HB_OFF,  4,  64, 230400, true,  true,  false>(p.wpack, p.Bb[3], s_act, nullptr, p0, wave, lane, pf);
    pf = prefetch< 4, 242688, 2>(p.wpack, wave, lane);
    __syncthreads();
    mlayer< 64,  HB_OFF, HA_OFF,  2,  32, 242688, true,  true,  false>(p.wpack, p.Bb[4], s_act, nullptr, p0, wave, lane, pf);
    pf = prefetch< 3, 246784, 1>(p.wpack, wave, lane);
    __syncthreads();
    mlayer< 32,  HA_OFF, HB_OFF,  1,  16, 246784, true,  true,  false>(p.wpack, p.Bb[5], s_act, nullptr, p0, wave, lane, pf);
    pf = prefetch< 1, 248320, 1>(p.wpack, wave, lane);
    __syncthreads();
    mlayer< 32,  HB_OFF, 0,       1,   2, 248320, false, false, true >(p.wpack, p.Bb[6], s_act, p.out,   p0, wave, lane, pf);
}

extern "C" void kernel_launch(void* const* d_in, const int* in_sizes, int n_in,
                              void* d_out, int out_size, void* d_ws, size_t ws_size,
                              hipStream_t stream)
{
    WPtrs wp;
    for (int l = 0; l < 7; ++l) wp.W[l] = (const float*)d_in[4 + 2 * l];

    MainParams p;
    p.lr    = (const float*)d_in[0];
    p.ctx   = (const float*)d_in[1];
    p.eps   = (const float*)d_in[2];
    p.coord = (const float*)d_in[3];
    for (int l = 0; l < 7; ++l) p.Bb[l] = (const float*)d_in[5 + 2 * l];
    p.wpack = (const u16*)d_ws;
    p.out   = (float*)d_out;

    // Opt in to large dynamic LDS (idempotent; not a stream op, capture-safe).
    hipFuncSetAttribute((const void*)cont_decoder_mfma,
                        hipFuncAttributeMaxDynamicSharedMemorySize, LDSBYTES);

    hipLaunchKernelGGL(pack_weights, dim3(122), dim3(256), 0, stream, wp, (u16*)d_ws);
    hipLaunchKernelGGL(cont_decoder_mfma, dim3(GRIDX), dim3(NTH), LDSBYTES, stream, p);
}

// Round 10
// 217.330 us; speedup vs baseline: 1.0467x; 1.0467x over previous
//
#include <hip/hip_runtime.h>

// ============================================================================
// ContDecoder on MI355X — bf16 MFMA, round 12: asm-volatile counted-vmcnt ring.
// MPTS=32, 1024 threads (16 waves), 55.8 KB dynamic LDS, 2 blocks/CU.
//
// Model (r4-r11): weight stream from L2 paces the kernel (~48 B/cyc/CU of
// ~64 B/cyc port) and each wave holds only 1 load in flight (VGPR 28;
// compiler re-sinks every source-level pipeline: r5/r6/r8/r11). Fix via the
// only mechanism the compiler cannot undo: asm volatile global_load_dwordx4
// ring (depth 3) + counted s_waitcnt vmcnt(2) + sched_barrier(0) (rule #18).
// Counted waits are oldest-first, so stale prior VMEM only over-waits: safe.
// A-frags double-buffered 1 step ahead; "memory" on waits pins ds_reads
// above the wait they precede -> LDS latency hides under the vmcnt wait.
// Base = r8 (best, 144.7us): 16x16x32, swapped mfma(W,X)->D[n,pt],
// ds_write_b64 epilogue + float4 bias, two-phase prologue. SGB stream and
// r11's prefetch/prologue-merge dropped (both null/negative).
//
// LDS row layout per point (bf16): [xin 0..64 | hA 64..608 | hB 608..864],
// stride 872 elems. Stale bytes in reused regions are masked by zero-packed
// weight rows; pad neurons get bias 0 so they write exact zeros.
// ============================================================================

#define NTH     1024
#define NWAVES  16
#define MPTS    32              // points per block (2 m-tiles of 16)
#define MTILES  (MPTS / 16)
#define SROW    872             // LDS row stride in bf16 elems
#define XIN_OFF 0
#define HA_OFF  64
#define HB_OFF  608
#define NPOINTS (8 * 16384)
#define GRIDX   (NPOINTS / MPTS)   // 4096 blocks
#define LDSBYTES (MPTS * SROW * 2) // 55808 -> 2 blocks/CU

typedef short          short8  __attribute__((ext_vector_type(8)));
typedef short          short4v __attribute__((ext_vector_type(4)));
typedef float          f32x4   __attribute__((ext_vector_type(4)));
typedef unsigned short u16;

__device__ __forceinline__ u16 f2bf(float f) {
    unsigned int u = __builtin_bit_cast(unsigned int, f);
    u += 0x7fffu + ((u >> 16) & 1u);        // round-to-nearest-even
    return (u16)(u >> 16);
}

template<int N>
__device__ __forceinline__ void waitvm() {
    if constexpr (N == 0)      asm volatile("s_waitcnt vmcnt(0)" ::: "memory");
    else if constexpr (N == 1) asm volatile("s_waitcnt vmcnt(1)" ::: "memory");
    else                       asm volatile("s_waitcnt vmcnt(2)" ::: "memory");
}

// ---------------------------------------------------------------------------
// Packed-weight geometry (16B fragments of 8 bf16). frag (l, nt, s, lane)
// holds B[s*32 + (lane>>4)*8 + j][nt*16 + (lane&15)], j=0..7, zero-padded.
// Identical byte layout as A- or B-operand of mfma_16x16x32 (HW-verified:
// r6/r7/r8 swapped-operand kernels passed). Same pack as r4..r11.
//   l : KHpad KSteps Ntiles  frag_base
//   0 :    0    2     33        0
//   1 :  544   19     16     4224
//   2 :  256   10      8    23680
//   3 :  128    6      4    28800
//   4 :   64    4      2    30336
//   5 :   32    3      1    30848
//   6 :   32    1      1    31040   total 31104 frags = 497664 B in d_ws
// ---------------------------------------------------------------------------
__constant__ int pk_base8[8] = {0, 4224, 23680, 28800, 30336, 30848, 31040, 31104};
__constant__ int pk_ks[7]    = {2, 19, 10, 6, 4, 3, 1};
__constant__ int pk_khp[7]   = {0, 544, 256, 128, 64, 32, 32};
__constant__ int pk_kact[7]  = {0, 516, 256, 128, 64, 32, 16};
__constant__ int pk_nact[7]  = {516, 256, 128, 64, 32, 16, 2};

struct WPtrs { const float* W[7]; };

__global__ void pack_weights(WPtrs wp, u16* __restrict__ out)
{
    const int f = blockIdx.x * blockDim.x + threadIdx.x;
    if (f >= 31104) return;
    int l = 0;
    while (l < 6 && f >= pk_base8[l + 1]) ++l;
    const int r    = f - pk_base8[l];
    const int lane = r & 63;
    const int t    = r >> 6;
    const int ks   = pk_ks[l];
    const int s    = t % ks;
    const int nt   = t / ks;
    const int n    = nt * 16 + (lane & 15);
    const int k0   = s * 32 + (lane >> 4) * 8;
    const int nact = pk_nact[l];
    const int khp  = pk_khp[l];
    const int kact = pk_kact[l];
    const float* W = wp.W[l];

    union { short8 v; u16 e[8]; } frag;
#pragma unroll
    for (int j = 0; j < 8; ++j) {
        const int k = k0 + j;
        float v = 0.0f;
        if (n < nact) {
            if (k < khp) {
                if (k < kact) v = W[k * nact + n];
            } else {
                const int xr = k - khp;
                if (xr < 37) v = W[(kact + xr) * nact + n];
            }
        }
        frag.e[j] = f2bf(v);
    }
    *(short8*)(out + (size_t)f * 8) = frag.v;
}

// ---------------------------------------------------------------------------
// One MLP layer, r8 mapping: wave w handles n-tiles {w, w+16, ...} < NT,
// both m-tiles (MS=2). K-loop: asm-volatile weight-load ring depth D=3 with
// counted vmcnt waits; A-frags (LDS) double-buffered one step ahead.
// Swapped operands: D[n,pt]: col pt = lane&15, row n = (lane>>4)*4 + r.
// ---------------------------------------------------------------------------
template<int KHP, int HSEG, int OSEG, int NT, int NACT, int LBASE,
         bool XIN, bool RELU, bool GOUT>
__device__ __forceinline__ void mlayer(const u16* __restrict__ wpack,
                                       const float* __restrict__ bias,
                                       u16* __restrict__ s_act,
                                       float* __restrict__ gout, int p0,
                                       int wave, int lane)
{
    constexpr int KHS = KHP / 32;
    constexpr int KS  = KHS + (XIN ? 2 : 0);
    constexpr int D   = (KS < 3) ? KS : 3;   // ring depth
    constexpr int MS  = MTILES;              // 2 m-tiles per wave
    const int lm = lane & 15;
    const int lq = lane >> 4;
    const u16* wl = wpack + LBASE + lane * 8;

    const u16* arow[MS];
#pragma unroll
    for (int m = 0; m < MS; ++m)
        arow[m] = s_act + (m * 16 + lm) * SROW + lq * 8;

#define ABOFF(s_) (((s_) < KHS) ? (HSEG + (s_) * 32) : (XIN_OFF + ((s_) - KHS) * 32))

    for (int nt = wave; nt < NT; nt += NWAVES) {
        const u16* bp = wl + (size_t)nt * KS * 512;

        f32x4 acc[MS];
#pragma unroll
        for (int m = 0; m < MS; ++m)
            acc[m] = (f32x4){0.f, 0.f, 0.f, 0.f};

        // ---- ring prologue: issue D weight loads (cannot be sunk) ----
        short8 ring[D];
#pragma unroll
        for (int d = 0; d < D; ++d)
            asm volatile("global_load_dwordx4 %0, %1, off"
                         : "=v"(ring[d])
                         : "v"((const void*)(bp + (size_t)d * 512)));

        // ---- A double-buffer: step 0 ----
        short8 abuf[2][MS];
#pragma unroll
        for (int m = 0; m < MS; ++m)
            abuf[0][m] = *(const short8*)(arow[m] + ABOFF(0));

#pragma unroll
        for (int s = 0; s < KS; ++s) {
            // A for step s+1 (pinned above the wait below by its mem clobber)
            if (s + 1 < KS) {
#pragma unroll
                for (int m = 0; m < MS; ++m)
                    abuf[(s + 1) & 1][m] = *(const short8*)(arow[m] + ABOFF(s + 1));
            }
            // counted wait: w = min(D-1, loads issued after s)
            const int rem = KS - 1 - s;
            if (D >= 3 && rem >= 2)      waitvm<2>();
            else if (D >= 2 && rem >= 1) waitvm<1>();
            else                         waitvm<0>();
            __builtin_amdgcn_sched_barrier(0);   // rule #18: no MFMA hoisting
#pragma unroll
            for (int m = 0; m < MS; ++m)
                acc[m] = __builtin_amdgcn_mfma_f32_16x16x32_bf16(
                             ring[s % D], abuf[s & 1][m], acc[m], 0, 0, 0);
            // reissue the consumed slot for step s+D
            if (s + D < KS)
                asm volatile("global_load_dwordx4 %0, %1, off"
                             : "=v"(ring[s % D])
                             : "v"((const void*)(bp + (size_t)(s + D) * 512)));
        }

        // ---- epilogue (ring drained: last wait was vmcnt(0)) ----
        const int bn = nt * 16 + lq * 4;
        float bv[4];
        if (bn + 4 <= NACT) {
            const f32x4 b4 = *(const f32x4*)(bias + bn);
            bv[0] = b4[0]; bv[1] = b4[1]; bv[2] = b4[2]; bv[3] = b4[3];
        } else {
#pragma unroll
            for (int r = 0; r < 4; ++r)
                bv[r] = (bn + r < NACT) ? bias[bn + r] : 0.f;
        }
        if (GOUT) {
            if (lq == 0) {             // only n=0,1 valid (NACT=2)
#pragma unroll
                for (int m = 0; m < MS; ++m) {
                    float2 o;
                    o.x = acc[m][0] + bv[0];
                    o.y = acc[m][1] + bv[1];
                    *(float2*)(gout + (size_t)(p0 + m * 16 + lm) * 2) = o;
                }
            }
        } else {
#pragma unroll
            for (int m = 0; m < MS; ++m) {
                short4v o;
#pragma unroll
                for (int r = 0; r < 4; ++r) {
                    float v = acc[m][r] + bv[r];
                    if (RELU) v = fmaxf(v, 0.f);
                    o[r] = (short)f2bf(v);
                }
                *(short4v*)(s_act + (size_t)(m * 16 + lm) * SROW + OSEG + bn) = o;
            }
        }
    }
#undef ABOFF
}

struct MainParams {
    const float* lr;     // [B,2,64,64]
    const float* ctx;    // [B,32,64,64]
    const float* eps;    // [B,64,64]
    const float* coord;  // [B,N,2]
    const float* Bb[7];  // biases (fp32)
    const u16*   wpack;  // packed bf16 weights in d_ws
    float*       out;    // [B,N,2]
};

__global__ __launch_bounds__(NTH, 8)   // 8 waves/EU = 32 waves/CU = 2 blocks
void cont_decoder_mfma(MainParams p)
{
    extern __shared__ u16 s_act[];         // MPTS*SROW bf16 = 55808 B
    __shared__ int   s_x0[MPTS], s_y0[MPTS];
    __shared__ float s_wx[MPTS], s_wy[MPTS];

    const int tid  = threadIdx.x;
    const int wave = tid >> 6;
    const int lane = tid & 63;
    const int p0   = blockIdx.x * MPTS;
    const int b    = p0 >> 14;             // 16384 points per batch

    // ---- zero pad regions: xin[37..64) and hA[528..544) (cols 592..608) ----
    for (int i = tid; i < MPTS * 43; i += NTH) {
        const int pt = i / 43, c = i % 43;
        const int col = (c < 27) ? (37 + c) : (592 + (c - 27));
        s_act[pt * SROW + col] = 0;
    }

    // ---- bilinear params + coord features ----
    if (tid < MPTS) {
        const int pt = p0 + tid;
        const float cx = p.coord[2 * pt];
        const float cy = p.coord[2 * pt + 1];
        const float gx = (cx + 1.0f) * 32.0f - 0.5f;   // align_corners=False
        const float gy = (cy + 1.0f) * 32.0f - 0.5f;
        const float fx0 = floorf(gx), fy0 = floorf(gy);
        s_x0[tid] = (int)fx0;
        s_y0[tid] = (int)fy0;
        s_wx[tid] = gx - fx0;
        s_wy[tid] = gy - fy0;
        s_act[tid * SROW + 32] = f2bf(cx);
        s_act[tid * SROW + 33] = f2bf(cy);
    }
    __syncthreads();

    // ---- sample 35 channels/point (ref swaps spatial axes: val = g[b,c,x,y]) ----
    for (int idx = tid; idx < MPTS * 35; idx += NTH) {
        const int t = idx / 35;
        const int c = idx % 35;
        const float* base;
        int col;
        if (c < 32)      { base = p.ctx + (size_t)(b * 32 + c) * 4096;       col = c; }
        else if (c < 34) { base = p.lr  + (size_t)(b * 2 + (c - 32)) * 4096; col = 34 + (c - 32); }
        else             { base = p.eps + (size_t)b * 4096;                   col = 36; }

        const int   x0 = s_x0[t], y0 = s_y0[t];
        const float wx = s_wx[t], wy = s_wy[t];
        const int x1 = x0 + 1, y1 = y0 + 1;
        const bool xv0 = (x0 >= 0) & (x0 < 64);
        const bool xv1 = (x1 >= 0) & (x1 < 64);
        const bool yv0 = (y0 >= 0) & (y0 < 64);
        const bool yv1 = (y1 >= 0) & (y1 < 64);
        const int xc0 = min(max(x0, 0), 63), xc1 = min(max(x1, 0), 63);
        const int yc0 = min(max(y0, 0), 63), yc1 = min(max(y1, 0), 63);

        const float w00 = (1.0f - wx) * (1.0f - wy) * ((xv0 && yv0) ? 1.0f : 0.0f);
        const float w10 = wx * (1.0f - wy)          * ((xv1 && yv0) ? 1.0f : 0.0f);
        const float w01 = (1.0f - wx) * wy          * ((xv0 && yv1) ? 1.0f : 0.0f);
        const float w11 = wx * wy                   * ((xv1 && yv1) ? 1.0f : 0.0f);

        const float val = w00 * base[xc0 * 64 + yc0]
                        + w10 * base[xc1 * 64 + yc0]
                        + w01 * base[xc0 * 64 + yc1]
                        + w11 * base[xc1 * 64 + yc1];
        s_act[t * SROW + col] = f2bf(val);
    }
    __syncthreads();

    // ---- MLP:  xin(37p64) ->W0-> hA(516p528) ->W1-> hB(256) ->W2-> hA(128)
    //            ->W3-> hB(64) ->W4-> hA(32) ->W5-> hB(16) ->W6-> out(2)
    //       KHP  HSEG    OSEG    NT  NACT LBASE(elems)  XIN   RELU   GOUT
    mlayer<  0,  HA_OFF, HA_OFF, 33, 516, 0,      true,  true,  false>(p.wpack, p.Bb[0], s_act, nullptr, p0, wave, lane);
    __syncthreads();
    mlayer<544,  HA_OFF, HB_OFF, 16, 256, 33792,  true,  true,  false>(p.wpack, p.Bb[1], s_act, nullptr, p0, wave, lane);
    __syncthreads();
    mlayer<256,  HB_OFF, HA_OFF,  8, 128, 189440, true,  true,  false>(p.wpack, p.Bb[2], s_act, nullptr, p0, wave, lane);
    __syncthreads();
    mlayer<128,  HA_OFF, HB_OFF,  4,  64, 230400, true,  true,  false>(p.wpack, p.Bb[3], s_act, nullptr, p0, wave, lane);
    __syncthreads();
    mlayer< 64,  HB_OFF, HA_OFF,  2,  32, 242688, true,  true,  false>(p.wpack, p.Bb[4], s_act, nullptr, p0, wave, lane);
    __syncthreads();
    mlayer< 32,  HA_OFF, HB_OFF,  1,  16, 246784, true,  true,  false>(p.wpack, p.Bb[5], s_act, nullptr, p0, wave, lane);
    __syncthreads();
    mlayer< 32,  HB_OFF, 0,       1,   2, 248320, false, false, true >(p.wpack, p.Bb[6], s_act, p.out,   p0, wave, lane);
}

extern "C" void kernel_launch(void* const* d_in, const int* in_sizes, int n_in,
                              void* d_out, int out_size, void* d_ws, size_t ws_size,
                              hipStream_t stream)
{
    WPtrs wp;
    for (int l = 0; l < 7; ++l) wp.W[l] = (const float*)d_in[4 + 2 * l];

    MainParams p;
    p.lr    = (const float*)d_in[0];
    p.ctx   = (const float*)d_in[1];
    p.eps   = (const float*)d_in[2];
    p.coord = (const float*)d_in[3];
    for (int l = 0; l < 7; ++l) p.Bb[l] = (const float*)d_in[5 + 2 * l];
    p.wpack = (const u16*)d_ws;
    p.out   = (float*)d_out;

    // Opt in to large dynamic LDS (idempotent; not a stream op, capture-safe).
    hipFuncSetAttribute((const void*)cont_decoder_mfma,
                        hipFuncAttributeMaxDynamicSharedMemorySize, LDSBYTES);

    hipLaunchKernelGGL(pack_weights, dim3(122), dim3(256), 0, stream, wp, (u16*)d_ws);
    hipLaunchKernelGGL(cont_decoder_mfma, dim3(GRIDX), dim3(NTH), LDSBYTES, stream, p);
}